// Round 4
// baseline (306.135 us; speedup 1.0000x reference)
//
#include <hip/hip_runtime.h>
#include <hip/hip_bf16.h>

// Problem constants
#define B   256
#define N   100
#define D   768
#define R   80
#define RPB 8            // rows handled per block
#define THRESHOLD 0.5f

// Native clang vector type (required by __builtin_nontemporal_*)
typedef float v4f __attribute__((ext_vector_type(4)));

// Output layout (flat float32 offsets, in return order)
#define SZ_VIS    ((long)B * R * D)            // 15,728,640
#define OFF_VIS   0L
#define OFF_TXT   (OFF_VIS + SZ_VIS)           // 15,728,640
#define OFF_TMASK (OFF_TXT + SZ_VIS)           // 31,457,280
#define OFF_IMASK (OFF_TMASK + (long)B*(R+1))  // 31,478,016
#define OFF_RR    (OFF_IMASK + (long)B*(R+1))  // 31,498,752
#define OFF_LAB   (OFF_RR + (long)B*R)         // 31,519,232

// Single fused kernel.
// grid = (R/RPB, B) = (10, 256); block = 192 threads (D/4 float4 lanes).
// Load phase issues all 16 float4 loads back-to-back (max MLP), then a
// store phase writes them non-temporally (pure streaming, no L2 reuse).
__global__ __launch_bounds__(192) void fused_kernel(
    const float* __restrict__ vis,    // (B, N, 1, D)
    const float* __restrict__ txt,    // (B, N, 1, D)
    const float* __restrict__ lab_in, // (B, N)
    const float* __restrict__ rr_in,  // (B, N)
    float* __restrict__ out)
{
    const int b  = blockIdx.y;
    const int r0 = blockIdx.x * RPB;
    const int t  = threadIdx.x;

    __shared__ float rrs[R];
    __shared__ int   order_s[RPB];
    __shared__ int   cnt_s;
    __shared__ int   zero_s;

    if (t < R) rrs[t] = rr_in[b * N + t];
    __syncthreads();

    if (t == 0) {
        int c = 0;
        int allz = 1;   // zero_rows <=> all rr < 0.5 (rr>=0.5 -> rr_mod=rr!=0)
        for (int i = 0; i < R; ++i) {
            float v = rrs[i];
            if (v >= THRESHOLD) allz = 0;
            if (v > THRESHOLD) {
                int rel = c - r0;
                if (rel >= 0 && rel < RPB) order_s[rel] = i;
                c++;
            }
        }
        cnt_s  = c;
        zero_s = allz;
    }
    __syncthreads();

    const int cnt = cnt_s;

    // ---- load phase: all 16 float4 loads in flight ----
    v4f va[RPB], xa[RPB];
    #pragma unroll
    for (int j = 0; j < RPB; ++j) {
        va[j] = (v4f){0.f, 0.f, 0.f, 0.f};
        xa[j] = va[j];
        if (r0 + j < cnt) {            // uniform across the block for row j
            const long in_idx = ((long)b * N + order_s[j]) * D + t * 4;
            va[j] = __builtin_nontemporal_load((const v4f*)(vis + in_idx));
            xa[j] = __builtin_nontemporal_load((const v4f*)(txt + in_idx));
        }
    }

    // ---- store phase: streaming, non-temporal ----
    const long o0 = ((long)b * R + r0) * D + t * 4;
    #pragma unroll
    for (int j = 0; j < RPB; ++j) {
        const long o = o0 + (long)j * D;
        __builtin_nontemporal_store(va[j], (v4f*)(out + OFF_VIS + o));
        __builtin_nontemporal_store(xa[j], (v4f*)(out + OFF_TXT + o));
    }

    // Small outputs: one block per batch handles them.
    if (r0 == 0) {
        if (t < R) {
            out[OFF_LAB + (long)b * R + t] = lab_in[b * N + t];
            float v  = rrs[t];
            float rm = (v < THRESHOLD) ? 0.0f : v;
            if (t == 0 && zero_s) rm = 1.0f;
            out[OFF_RR + (long)b * R + t] = rm;
        }
        if (t <= R) {  // R+1 = 81 mask entries
            float tm = (t <= cnt) ? 1.0f : 0.0f;
            out[OFF_TMASK + (long)b * (R + 1) + t] = tm;
            out[OFF_IMASK + (long)b * (R + 1) + t] = (b == B - 1) ? tm : 1.0f;
        }
    }
}

extern "C" void kernel_launch(void* const* d_in, const int* in_sizes, int n_in,
                              void* d_out, int out_size, void* d_ws, size_t ws_size,
                              hipStream_t stream) {
    // inputs (setup_inputs order):
    // 0: mean_pooling_vec (B,D)        -- unused
    // 1: merge_text_vec (B,D)          -- unused
    // 2: retrieved_visual_feature_embedding_cls (B,N,1,D)
    // 3: retrieved_textual_feature_embedding    (B,N,1,D)
    // 4: retrieved_label_list (B,N)
    // 5: RRCP (B,N)
    const float* vis = (const float*)d_in[2];
    const float* txt = (const float*)d_in[3];
    const float* lab = (const float*)d_in[4];
    const float* rr  = (const float*)d_in[5];
    float* out = (float*)d_out;

    dim3 grid(R / RPB, B);   // (10, 256)
    fused_kernel<<<grid, 192, 0, stream>>>(vis, txt, lab, rr, out);
}

// Round 5
// 241.654 us; speedup vs baseline: 1.2668x; 1.2668x over previous
//
#include <hip/hip_runtime.h>
#include <hip/hip_bf16.h>

// Problem constants
#define B   256
#define N   100
#define D   768
#define R   80
#define RPB 4            // rows handled per block (4 keeps VGPR pressure low)
#define THRESHOLD 0.5f

// Native clang vector type (required by __builtin_nontemporal_*)
typedef float v4f __attribute__((ext_vector_type(4)));

// Output layout (flat float32 offsets, in return order)
#define SZ_VIS    ((long)B * R * D)            // 15,728,640
#define OFF_VIS   0L
#define OFF_TXT   (OFF_VIS + SZ_VIS)           // 15,728,640
#define OFF_TMASK (OFF_TXT + SZ_VIS)           // 31,457,280
#define OFF_IMASK (OFF_TMASK + (long)B*(R+1))  // 31,478,016
#define OFF_RR    (OFF_IMASK + (long)B*(R+1))  // 31,498,752
#define OFF_LAB   (OFF_RR + (long)B*R)         // 31,519,232

// Single fused kernel.
// grid = (R/RPB, B) = (20, 256) = 5120 blocks; block = 192 threads (D/4).
// Interleaved load->store per row (keeps live registers low -> occupancy),
// plain loads (inputs are LLC-resident after the harness restore),
// non-temporal stores (output never re-read; don't evict inputs from LLC).
__global__ __launch_bounds__(192) void fused_kernel(
    const float* __restrict__ vis,    // (B, N, 1, D)
    const float* __restrict__ txt,    // (B, N, 1, D)
    const float* __restrict__ lab_in, // (B, N)
    const float* __restrict__ rr_in,  // (B, N)
    float* __restrict__ out)
{
    const int b  = blockIdx.y;
    const int r0 = blockIdx.x * RPB;
    const int t  = threadIdx.x;

    __shared__ float rrs[R];
    __shared__ int   order_s[RPB];
    __shared__ int   cnt_s;
    __shared__ int   zero_s;

    if (t < R) rrs[t] = rr_in[b * N + t];
    __syncthreads();

    if (t == 0) {
        int c = 0;
        int allz = 1;   // zero_rows <=> all rr < 0.5 (rr>=0.5 -> rr_mod=rr!=0)
        for (int i = 0; i < R; ++i) {
            float v = rrs[i];
            if (v >= THRESHOLD) allz = 0;
            if (v > THRESHOLD) {
                int rel = c - r0;
                if (rel >= 0 && rel < RPB) order_s[rel] = i;
                c++;
            }
        }
        cnt_s  = c;
        zero_s = allz;
    }
    __syncthreads();

    const int cnt = cnt_s;
    const long o0 = ((long)b * R + r0) * D + t * 4;

    #pragma unroll
    for (int j = 0; j < RPB; ++j) {
        v4f v = (v4f){0.f, 0.f, 0.f, 0.f};
        v4f x = v;
        if (r0 + j < cnt) {            // uniform across the block for row j
            const long in_idx = ((long)b * N + order_s[j]) * D + t * 4;
            v = *(const v4f*)(vis + in_idx);
            x = *(const v4f*)(txt + in_idx);
        }
        const long o = o0 + (long)j * D;
        __builtin_nontemporal_store(v, (v4f*)(out + OFF_VIS + o));
        __builtin_nontemporal_store(x, (v4f*)(out + OFF_TXT + o));
    }

    // Small outputs: one block per batch handles them.
    if (r0 == 0) {
        if (t < R) {
            out[OFF_LAB + (long)b * R + t] = lab_in[b * N + t];
            float v  = rrs[t];
            float rm = (v < THRESHOLD) ? 0.0f : v;
            if (t == 0 && zero_s) rm = 1.0f;
            out[OFF_RR + (long)b * R + t] = rm;
        }
        if (t <= R) {  // R+1 = 81 mask entries
            float tm = (t <= cnt) ? 1.0f : 0.0f;
            out[OFF_TMASK + (long)b * (R + 1) + t] = tm;
            out[OFF_IMASK + (long)b * (R + 1) + t] = (b == B - 1) ? tm : 1.0f;
        }
    }
}

extern "C" void kernel_launch(void* const* d_in, const int* in_sizes, int n_in,
                              void* d_out, int out_size, void* d_ws, size_t ws_size,
                              hipStream_t stream) {
    // inputs (setup_inputs order):
    // 0: mean_pooling_vec (B,D)        -- unused
    // 1: merge_text_vec (B,D)          -- unused
    // 2: retrieved_visual_feature_embedding_cls (B,N,1,D)
    // 3: retrieved_textual_feature_embedding    (B,N,1,D)
    // 4: retrieved_label_list (B,N)
    // 5: RRCP (B,N)
    const float* vis = (const float*)d_in[2];
    const float* txt = (const float*)d_in[3];
    const float* lab = (const float*)d_in[4];
    const float* rr  = (const float*)d_in[5];
    float* out = (float*)d_out;

    dim3 grid(R / RPB, B);   // (20, 256)
    fused_kernel<<<grid, 192, 0, stream>>>(vis, txt, lab, rr, out);
}